// Round 13
// baseline (287.564 us; speedup 1.0000x reference)
//
#include <hip/hip_runtime.h>
#include <hip/hip_bf16.h>
#include <cstddef>

// Problem constants
#define LL 1024
#define DD0 256
#define NDIR 6
#define NL 2
#define HH 8
#define PP 64
#define NN 32
#define KK 4
#define DI 512           // 2*D
#define DIN 1096         // 2*DI + 2*N + H
#define CONV_DIM 576     // DI + 2*N

// chunked scan config
#define QC 16            // chunk length
#define NC 64            // LL / QC
#define NCSH 6           // log2(NC)
#define QCH 8            // QC/2 (conv phase: 2 halves)

__constant__ int c_ord[6][3] = {{0,1,2},{0,2,1},{1,0,2},{1,2,0},{2,0,1},{2,1,0}};

typedef __attribute__((ext_vector_type(8))) short bf16x8;
typedef __attribute__((ext_vector_type(4))) float f32x4;

// ---------------- helpers ----------------
__device__ inline float blockReduceSum256(float v) {
    __shared__ float sred[4];
#pragma unroll
    for (int off = 1; off < 64; off <<= 1) v += __shfl_xor(v, off);
    int lane = threadIdx.x & 63, w = threadIdx.x >> 6;
    __syncthreads();               // protect sred from a previous call
    if (lane == 0) sred[w] = v;
    __syncthreads();
    return sred[0] + sred[1] + sred[2] + sred[3];
}

__device__ inline float siluf(float x) { return x / (1.f + expf(-x)); }

// round-to-nearest-even fp32 -> bf16 bits
__device__ inline unsigned short bf16_rn(float x) {
    unsigned u = __float_as_uint(x);
    unsigned r = (u + 0x7fffu + ((u >> 16) & 1u)) >> 16;
    return (unsigned short)r;
}
__device__ inline float bf16_to_f(unsigned short h) {
    return __uint_as_float(((unsigned)h) << 16);
}

// ---------------- sort (lexsort via rank counting, 4-way split) ----------------
__global__ __launch_bounds__(1024)
void sort_kernel(const int* __restrict__ coords, int* __restrict__ perm, int* __restrict__ rank) {
    int q = blockIdx.x, d = blockIdx.y;
    int tid = threadIdx.x;
    __shared__ unsigned keys[LL];
    __shared__ unsigned short part[256][5];
    int a0 = c_ord[d][0], a1 = c_ord[d][1], a2 = c_ord[d][2];
    {
        unsigned c0 = (unsigned)coords[tid*4 + a0];
        unsigned c1 = (unsigned)coords[tid*4 + a1];
        unsigned c2 = (unsigned)coords[tid*4 + a2];
        keys[tid] = (c0 << 22) | (c1 << 16) | (c2 << 10) | (unsigned)tid;
    }
    __syncthreads();
    int il = tid >> 2, jq = tid & 3;
    int i = q*256 + il;
    unsigned ki = keys[i];
    int r = 0;
    int j0 = jq*256;
#pragma unroll 8
    for (int j = j0; j < j0 + 256; ++j) r += (keys[j] < ki) ? 1 : 0;
    part[il][jq] = (unsigned short)r;
    __syncthreads();
    if (tid < 256) {
        int i2 = q*256 + tid;
        int rr = part[tid][0] + part[tid][1] + part[tid][2] + part[tid][3];
        perm[d*LL + rr] = i2;
        rank[d*LL + i2] = rr;
    }
}

// ---------------- fused gather + layer-0 layernorm -> residual + bf16 hi/lo ----------------
__global__ __launch_bounds__(256)
void gather_ln(const float* __restrict__ vectors, const int* __restrict__ perm,
               float* __restrict__ x, unsigned short* __restrict__ Yh,
               unsigned short* __restrict__ Yl,
               const float* __restrict__ g, const float* __restrict__ b) {
    int t = blockIdx.x, d = blockIdx.y, c = threadIdx.x;
    int src = perm[d*LL + t];
    float xv = vectors[(size_t)src*DD0 + c];
    x[((size_t)d*LL + t)*DD0 + c] = xv;
    float s = blockReduceSum256(xv);
    float s2 = blockReduceSum256(xv*xv);
    float mu = s / DD0;
    float var = s2 / DD0 - mu*mu;
    float inv = rsqrtf(var + 1e-5f);
    const float* gr = g + (size_t)d*NL*DD0;
    const float* br = b + (size_t)d*NL*DD0;
    float yv = (xv - mu) * inv * gr[c] + br[c];
    unsigned short h = bf16_rn(yv);
    Yh[((size_t)d*LL + t)*DD0 + c] = h;
    Yl[((size_t)d*LL + t)*DD0 + c] = bf16_rn(yv - bf16_to_f(h));
}

// ---------------- layernorm -> bf16 hi/lo split (layer 1) ----------------
__global__ __launch_bounds__(256)
void ln_split(const float* __restrict__ X, unsigned short* __restrict__ Yh,
              unsigned short* __restrict__ Yl,
              const float* __restrict__ g, const float* __restrict__ b,
              int dd, int rowsPerDir, int gstride) {
    int t = blockIdx.x, d = blockIdx.y;
    const float* xr = X + ((size_t)d*rowsPerDir + t)*dd;
    unsigned short* yh = Yh + ((size_t)d*rowsPerDir + t)*dd;
    unsigned short* yl = Yl + ((size_t)d*rowsPerDir + t)*dd;
    const float* gr = g + (size_t)d*gstride;
    const float* br = b + (size_t)d*gstride;
    float v[6];
    float s = 0.f, s2 = 0.f;
    int cnt = 0;
    for (int c = threadIdx.x; c < dd; c += 256) {
        float xv = xr[c];
        v[cnt++] = xv;
        s += xv; s2 += xv*xv;
    }
    float tot = blockReduceSum256(s);
    float tot2 = blockReduceSum256(s2);
    float mu = tot / dd;
    float var = tot2 / dd - mu*mu;
    float inv = rsqrtf(var + 1e-5f);
    cnt = 0;
    for (int c = threadIdx.x; c < dd; c += 256) {
        float yv = (v[cnt++] - mu) * inv * gr[c] + br[c];
        unsigned short h = bf16_rn(yv);
        yh[c] = h;
        yl[c] = bf16_rn(yv - bf16_to_f(h));
    }
}

// ---------------- fused inverse-permute concat + fuse layernorm ----------------
__global__ __launch_bounds__(256)
void ln_concat(const float* __restrict__ x, const int* __restrict__ rank,
               unsigned short* __restrict__ Yh, unsigned short* __restrict__ Yl,
               const float* __restrict__ g, const float* __restrict__ b) {
    int t = blockIdx.x, tid = threadIdx.x;
    float v[NDIR];
    float s = 0.f, s2 = 0.f;
#pragma unroll
    for (int d = 0; d < NDIR; ++d) {
        int r = rank[d*LL + t];
        float xv = x[((size_t)d*LL + r)*DD0 + tid];
        v[d] = xv;
        s += xv; s2 += xv*xv;
    }
    float tot = blockReduceSum256(s);
    float tot2 = blockReduceSum256(s2);
    const int dd = NDIR*DD0;
    float mu = tot / dd;
    float var = tot2 / dd - mu*mu;
    float inv = rsqrtf(var + 1e-5f);
#pragma unroll
    for (int d = 0; d < NDIR; ++d) {
        int c = d*DD0 + tid;
        float yv = (v[d] - mu) * inv * g[c] + b[c];
        unsigned short h = bf16_rn(yv);
        Yh[(size_t)t*dd + c] = h;
        Yl[(size_t)t*dd + c] = bf16_rn(yv - bf16_to_f(h));
    }
}

// ---------------- merged transpose+split for all three weights (1 dispatch) ----------
__global__ __launch_bounds__(256)
void tsplit_all(const float* __restrict__ Wi, const float* __restrict__ Wo,
                const float* __restrict__ Wf,
                unsigned short* __restrict__ WinTh, unsigned short* __restrict__ WinTl,
                unsigned short* __restrict__ WoutTh, unsigned short* __restrict__ WoutTl,
                unsigned short* __restrict__ fWTh, unsigned short* __restrict__ fWTl) {
    int bid = blockIdx.x;
    const float* W; unsigned short *Th, *Tl; int Kd, Nd, bx, by, bz;
    if (bid < 3360) {
        int r = bid; W = Wi; Th = WinTh; Tl = WinTl; Kd = DD0; Nd = DIN;
        bx = r % 35; r /= 35; by = r & 7; bz = r >> 3;
    } else if (bid < 4896) {
        int r = bid - 3360; W = Wo; Th = WoutTh; Tl = WoutTl; Kd = DI; Nd = DD0;
        bx = r & 7; r >>= 3; by = r & 15; bz = r >> 4;
    } else {
        int r = bid - 4896; W = Wf; Th = fWTh; Tl = fWTl; Kd = NDIR*DD0; Nd = DD0;
        bx = r & 7; by = r >> 3; bz = 0;
    }
    __shared__ float tile[32][33];
    int j0 = bx * 32;   // N
    int i0 = by * 32;   // K
    int c = threadIdx.x & 31, r8 = threadIdx.x >> 5;
    const float* Wz = W + (size_t)bz * Kd * Nd;
    unsigned short* Thz = Th + (size_t)bz * Nd * Kd;
    unsigned short* Tlz = Tl + (size_t)bz * Nd * Kd;
#pragma unroll
    for (int s = 0; s < 4; ++s) {
        int i = i0 + r8 + s*8;
        tile[r8 + s*8][c] = (i < Kd && (j0 + c) < Nd) ? Wz[(size_t)i*Nd + j0 + c] : 0.f;
    }
    __syncthreads();
#pragma unroll
    for (int s = 0; s < 4; ++s) {
        int j = j0 + r8 + s*8;   // output row (n)
        int i = i0 + c;          // output col (k)
        if (j < Nd && i < Kd) {
            float xv = tile[c][r8 + s*8];
            unsigned short h = bf16_rn(xv);
            Thz[(size_t)j*Kd + i] = h;
            Tlz[(size_t)j*Kd + i] = bf16_rn(xv - bf16_to_f(h));
        }
    }
}

// ---------------- split-precision MFMA GEMM, LDS + 2-deep prefetch pipeline ----------
// (R10-proven: BOTH operands LDS-staged — per-lane-strided direct fragment
// loads fragment into 16 cache lines/wave and lose, even when L2-resident.)
template<int MODE, int BM>
__global__ __launch_bounds__(256)
void mfma_gemm(const unsigned short* __restrict__ Ahg, const unsigned short* __restrict__ Alg,
               const unsigned short* __restrict__ Bhg, const unsigned short* __restrict__ Blg,
               float* __restrict__ Cg, int N, int K,
               size_t sA, size_t sB, size_t sC, const float* __restrict__ bias,
               int ksplit) {
    constexpr int MF = BM / 32;          // m-fragments per wave
    __shared__ unsigned short AhS[2][BM][40];
    __shared__ unsigned short AlS[2][BM][40];
    __shared__ unsigned short BhS[2][64][40];
    __shared__ unsigned short BlS[2][64][40];
    const unsigned short* Azh = Ahg + (MODE == 3 ? 0 : (size_t)blockIdx.z * sA);
    const unsigned short* Azl = Alg + (MODE == 3 ? 0 : (size_t)blockIdx.z * sA);
    const unsigned short* Bzh = Bhg + (MODE == 3 ? 0 : (size_t)blockIdx.z * sB);
    const unsigned short* Bzl = Blg + (MODE == 3 ? 0 : (size_t)blockIdx.z * sB);
    float* Cz = Cg + (size_t)blockIdx.z * sC;
    int row0 = blockIdx.y * BM;
    int col0 = blockIdx.x * 64;
    int tid = threadIdx.x;
    int lane = tid & 63, wid = tid >> 6;
    int mbase = (wid >> 1) * (BM/2), nbase = (wid & 1) * 32;
    int lr = lane & 15, lk = (lane >> 4) * 8;

    int ar0 = tid >> 2;
    int ar1 = 64 + (tid >> 2);
    int ac  = (tid & 3) * 8;
    int brow = tid >> 2;
    int bc8 = (tid & 3) * 8;
    bool bvalid = (col0 + brow) < N;
    const uint4 z4 = {0u,0u,0u,0u};

    f32x4 acc[MF][2];
#pragma unroll
    for (int m = 0; m < MF; ++m)
#pragma unroll
        for (int n = 0; n < 2; ++n) acc[m][n] = (f32x4){0.f, 0.f, 0.f, 0.f};

    uint4 s0a0, s0a1, s0l0, s0l1, s0bh, s0bl;
    uint4 s1a0, s1a1, s1l0, s1l1, s1bh, s1bl;

#define LOAD_TILE(Ra0,Ra1,Rl0,Rl1,Rbh,Rbl,kt) do {                          \
        size_t ka = (size_t)(kt) * 32;                                       \
        size_t g0 = (size_t)(row0 + ar0)*K + ka + ac;                        \
        Ra0 = *(const uint4*)(Azh + g0);                                     \
        Rl0 = *(const uint4*)(Azl + g0);                                     \
        if (BM == 128) {                                                     \
            size_t g1 = (size_t)(row0 + ar1)*K + ka + ac;                    \
            Ra1 = *(const uint4*)(Azh + g1);                                 \
            Rl1 = *(const uint4*)(Azl + g1);                                 \
        }                                                                    \
        if (bvalid) {                                                        \
            size_t gb = (size_t)(col0 + brow)*K + ka + bc8;                  \
            Rbh = *(const uint4*)(Bzh + gb);                                 \
            Rbl = *(const uint4*)(Bzl + gb);                                 \
        } else { Rbh = z4; Rbl = z4; }                                       \
    } while (0)

#define WRITE_TILE(buf,Ra0,Ra1,Rl0,Rl1,Rbh,Rbl) do {                         \
        *(uint4*)&AhS[buf][ar0][ac] = Ra0;                                   \
        *(uint4*)&AlS[buf][ar0][ac] = Rl0;                                   \
        if (BM == 128) {                                                     \
            *(uint4*)&AhS[buf][ar1 & (BM-1)][ac] = Ra1;                      \
            *(uint4*)&AlS[buf][ar1 & (BM-1)][ac] = Rl1;                      \
        }                                                                    \
        *(uint4*)&BhS[buf][brow][bc8] = Rbh;                                 \
        *(uint4*)&BlS[buf][brow][bc8] = Rbl;                                 \
    } while (0)

#define COMPUTE(buf) do {                                                    \
        bf16x8 afh[MF], afl[MF], bfh[2], bfl[2];                             \
        _Pragma("unroll")                                                    \
        for (int mf = 0; mf < MF; ++mf) {                                    \
            afh[mf] = *(const bf16x8*)&AhS[buf][mbase + mf*16 + lr][lk];     \
            afl[mf] = *(const bf16x8*)&AlS[buf][mbase + mf*16 + lr][lk];     \
        }                                                                    \
        _Pragma("unroll")                                                    \
        for (int nf = 0; nf < 2; ++nf) {                                     \
            bfh[nf] = *(const bf16x8*)&BhS[buf][nbase + nf*16 + lr][lk];     \
            bfl[nf] = *(const bf16x8*)&BlS[buf][nbase + nf*16 + lr][lk];     \
        }                                                                    \
        _Pragma("unroll")                                                    \
        for (int mf = 0; mf < MF; ++mf)                                      \
            _Pragma("unroll")                                                \
            for (int nf = 0; nf < 2; ++nf) {                                 \
                acc[mf][nf] = __builtin_amdgcn_mfma_f32_16x16x32_bf16(afh[mf], bfh[nf], acc[mf][nf], 0, 0, 0); \
                acc[mf][nf] = __builtin_amdgcn_mfma_f32_16x16x32_bf16(afh[mf], bfl[nf], acc[mf][nf], 0, 0, 0); \
                acc[mf][nf] = __builtin_amdgcn_mfma_f32_16x16x32_bf16(afl[mf], bfh[nf], acc[mf][nf], 0, 0, 0); \
            }                                                                \
    } while (0)

    int nt, kt0;
    if (MODE == 3) { nt = ksplit; kt0 = (int)blockIdx.z * ksplit; }
    else           { nt = K >> 5; kt0 = 0; }

    LOAD_TILE(s0a0, s0a1, s0l0, s0l1, s0bh, s0bl, kt0 + 0);
    LOAD_TILE(s1a0, s1a1, s1l0, s1l1, s1bh, s1bl, kt0 + 1);
    WRITE_TILE(0, s0a0, s0a1, s0l0, s0l1, s0bh, s0bl);
    __syncthreads();

    for (int t = 0; t < nt; t += 2) {
        if (t + 2 < nt) LOAD_TILE(s0a0, s0a1, s0l0, s0l1, s0bh, s0bl, kt0 + t + 2);
        COMPUTE(0);
        WRITE_TILE(1, s1a0, s1a1, s1l0, s1l1, s1bh, s1bl);
        __syncthreads();
        if (t + 3 < nt) LOAD_TILE(s1a0, s1a1, s1l0, s1l1, s1bh, s1bl, kt0 + t + 3);
        COMPUTE(1);
        if (t + 2 < nt) WRITE_TILE(0, s0a0, s0a1, s0l0, s0l1, s0bh, s0bl);
        __syncthreads();
    }

#undef LOAD_TILE
#undef WRITE_TILE
#undef COMPUTE

    int crb = (lane >> 4) * 4;
    int cco = lane & 15;
#pragma unroll
    for (int mf = 0; mf < MF; ++mf) {
#pragma unroll
        for (int nf = 0; nf < 2; ++nf) {
            int col = col0 + nbase + nf*16 + cco;
            if (col < N) {
#pragma unroll
                for (int r = 0; r < 4; ++r) {
                    int row = row0 + mbase + mf*16 + crb + r;
                    size_t o = (size_t)row*N + col;
                    float vv = acc[mf][nf][r];
                    if (MODE == 0 || MODE == 3) Cz[o] = vv;
                    else if (MODE == 1) Cz[o] += vv;
                    else {
                        vv += bias[col];
                        Cz[o] = 0.5f * vv * (1.f + erff(vv * 0.70710678118654752f));
                    }
                }
            }
        }
    }
}

// ---------------- split-K reduce + bias + gelu ----------------
__global__ __launch_bounds__(256)
void reduce_gelu(const float* __restrict__ pbuf, const float* __restrict__ bias,
                 float* __restrict__ out) {
    int t = blockIdx.x, c = threadIdx.x;
    size_t o = (size_t)t*DD0 + c;
    const size_t st = (size_t)LL*DD0;
    float v = pbuf[o] + pbuf[o + st] + pbuf[o + 2*st] + pbuf[o + 3*st] + bias[c];
    out[o] = 0.5f * v * (1.f + erff(v * 0.70710678118654752f));
}

// ---------------- FUSED conv(K=4)+silu + chunk-local selective scan ----------------
__global__ __launch_bounds__(256)
void conv_scan1(const float* __restrict__ zx, const float* __restrict__ conv_w,
                const float* __restrict__ conv_b, const float* __restrict__ dt_bias,
                const float* __restrict__ A_log, const float* __restrict__ Dp,
                float* __restrict__ ys, float* __restrict__ Cbuf,
                float* __restrict__ cstate, float* __restrict__ cumdec, int layer) {
    int bid = blockIdx.x;
    int c = bid & (NC - 1);
    int hd = bid >> NCSH;
    int d = hd >> 3, h = hd & 7;
    int tid = threadIdx.x;
    int t0 = c * QC;

    __shared__ float sxc[QC][132];   // cols 0..63 = xs slice, 64..95 = B, 96..127 = C
    __shared__ float sdt[QC];
    __shared__ float sdA[QC];

    const float* Z = zx + (size_t)d*LL*DIN;

    // ---- phase A: conv for 128 cols x QC t (2 halves of QCH) ----
    {
        int col = tid & 127;
        int half = tid >> 7;
        int tstart = t0 + half*QCH;
        int realc = (col < 64) ? (h*PP + col) : ((col < 96) ? (DI + (col-64)) : (DI + NN + (col-96)));
        int zxcol = DI + realc;
        const float* wr = conv_w + ((size_t)(d*NL + layer)*CONV_DIM + realc)*KK;
        float w0 = wr[0], w1 = wr[1], w2 = wr[2], w3 = wr[3];
        float bias = conv_b[(size_t)(d*NL + layer)*CONV_DIM + realc];
        float z0 = (tstart-3 >= 0) ? Z[(size_t)(tstart-3)*DIN + zxcol] : 0.f;
        float z1 = (tstart-2 >= 0) ? Z[(size_t)(tstart-2)*DIN + zxcol] : 0.f;
        float z2 = (tstart-1 >= 0) ? Z[(size_t)(tstart-1)*DIN + zxcol] : 0.f;
#pragma unroll
        for (int tt = 0; tt < QCH; ++tt) {
            int t = tstart + tt;
            float z3 = Z[(size_t)t*DIN + zxcol];
            float acc = bias;
            acc = fmaf(z0, w0, acc);
            acc = fmaf(z1, w1, acc);
            acc = fmaf(z2, w2, acc);
            acc = fmaf(z3, w3, acc);
            sxc[half*QCH + tt][col] = siluf(acc);
            z0 = z1; z1 = z2; z2 = z3;
        }
    }
    // ---- phase A2: dt / dA for this h ----
    if (tid < QC) {
        int t = t0 + tid;
        float v = Z[(size_t)t*DIN + (DIN - HH) + h] + dt_bias[(d*NL + layer)*HH + h];
        float sp = (v > 20.f) ? v : log1pf(expf(v));
        sdt[tid] = sp;
        sdA[tid] = expf(-expf(A_log[(d*NL + layer)*HH + h]) * sp);
    }
    __syncthreads();

    // ---- phase B: chunk-local scan from LDS ----
    int p = tid >> 2, g = tid & 3, n0 = g << 3;
    float dpv = Dp[(d*NL + layer)*HH + h];
    float* ysd = ys + (size_t)d*LL*DI + h*PP + p;
    float* cdd = cumdec + (size_t)d*LL*HH + h;
    float* Cbd = Cbuf + (size_t)d*LL*NN;

    float hs[8];
#pragma unroll
    for (int j = 0; j < 8; ++j) hs[j] = 0.f;
    float cum = 1.f;

    for (int tt = 0; tt < QC; ++tt) {
        float dtv = sdt[tt], dAv = sdA[tt];
        float xv = sxc[tt][p];
        float dtx = dtv * xv;
        float4 b0 = *(const float4*)&sxc[tt][64 + n0];
        float4 b1 = *(const float4*)&sxc[tt][64 + n0 + 4];
        float4 c0 = *(const float4*)&sxc[tt][96 + n0];
        float4 c1 = *(const float4*)&sxc[tt][96 + n0 + 4];
        float B[8] = {b0.x,b0.y,b0.z,b0.w,b1.x,b1.y,b1.z,b1.w};
        float Cv[8] = {c0.x,c0.y,c0.z,c0.w,c1.x,c1.y,c1.z,c1.w};
        float acc = 0.f;
#pragma unroll
        for (int j = 0; j < 8; ++j) {
            hs[j] = fmaf(dAv, hs[j], dtx * B[j]);
            acc = fmaf(hs[j], Cv[j], acc);
        }
        acc += __shfl_xor(acc, 1);
        acc += __shfl_xor(acc, 2);
        int t = t0 + tt;
        if (g == 0) ysd[(size_t)t*DI] = acc + dpv * xv;     // D-residual folded in
        else if (g == 2 && h == 0 && p < NN) Cbd[(size_t)t*NN + p] = sxc[tt][96 + p];
        cum *= dAv;
        if (tid == 0) cdd[(size_t)t*HH] = cum;
    }

    float* cs = cstate + (((size_t)(d*NC + c)*HH + h)*PP + p)*NN + n0;
    float4 s0 = {hs[0], hs[1], hs[2], hs[3]};
    float4 s1 = {hs[4], hs[5], hs[6], hs[7]};
    *(float4*)cs = s0;
    *(float4*)(cs + 4) = s1;
}

// ---------------- pass2: sequential fixup over chunk states ----------------
__global__ __launch_bounds__(256)
void scan_pass2(float* __restrict__ cstate, const float* __restrict__ cumdec) {
    int hd = blockIdx.x;
    int d = hd >> 3, h = hd & 7;
    int tid = threadIdx.x;
    int p = tid >> 2, g = tid & 3, n0 = g << 3;
    float carry[8];
#pragma unroll
    for (int j = 0; j < 8; ++j) carry[j] = 0.f;
    for (int c = 0; c < NC; ++c) {
        float* cs = cstate + (((size_t)(d*NC + c)*HH + h)*PP + p)*NN + n0;
        float4 s0 = *(const float4*)cs;
        float4 s1 = *(const float4*)(cs + 4);
        float4 w0 = {carry[0], carry[1], carry[2], carry[3]};
        float4 w1 = {carry[4], carry[5], carry[6], carry[7]};
        *(float4*)cs = w0;
        *(float4*)(cs + 4) = w1;
        float dec = cumdec[((size_t)d*LL + (c*QC + QC - 1))*HH + h];
        float s[8] = {s0.x,s0.y,s0.z,s0.w,s1.x,s1.y,s1.z,s1.w};
#pragma unroll
        for (int j = 0; j < 8; ++j) carry[j] = fmaf(dec, carry[j], s[j]);
    }
}

// ---------------- pass3: y[t] += cumdec[t] * (C[t] . h_init) ----------------
__global__ __launch_bounds__(256)
void scan_pass3(const float* __restrict__ Cbuf, const float* __restrict__ cumdec,
                const float* __restrict__ cstate, float* __restrict__ ys) {
    int bid = blockIdx.x;
    int c = bid & (NC - 1);
    if (c == 0) return;
    int hd = bid >> NCSH;
    int d = hd >> 3, h = hd & 7;
    int tid = threadIdx.x;
    int p = tid >> 2, g = tid & 3, n0 = g << 3;
    int t0 = c * QC;

    __shared__ float scd[QC];
    if (tid < QC) scd[tid] = cumdec[((size_t)d*LL + t0 + tid)*HH + h];

    const float* cs = cstate + (((size_t)(d*NC + c)*HH + h)*PP + p)*NN + n0;
    float4 h0 = *(const float4*)cs;
    float4 h1 = *(const float4*)(cs + 4);
    float hi[8] = {h0.x,h0.y,h0.z,h0.w,h1.x,h1.y,h1.z,h1.w};
    __syncthreads();

    const float* Cbd = Cbuf + (size_t)d*LL*NN;
    float* ysd = ys + (size_t)d*LL*DI + h*PP + p;

    for (int tt = 0; tt < QC; ++tt) {
        int t = t0 + tt;
        const float* row = Cbd + (size_t)t*NN;
        float4 c0 = *(const float4*)(row + n0);
        float4 c1 = *(const float4*)(row + n0 + 4);
        float Cv[8] = {c0.x,c0.y,c0.z,c0.w,c1.x,c1.y,c1.z,c1.w};
        float acc = 0.f;
#pragma unroll
        for (int j = 0; j < 8; ++j) acc = fmaf(hi[j], Cv[j], acc);
        acc += __shfl_xor(acc, 1);
        acc += __shfl_xor(acc, 2);
        if (g == 0) ysd[(size_t)t*DI] += scd[tt] * acc;
    }
}

// ---------------- gating + RMSNorm -> bf16 hi/lo split (float2-vectorized) --------
__global__ __launch_bounds__(256)
void gate_rms(const float* __restrict__ ys, const float* __restrict__ zx,
              const float* __restrict__ rms_g, unsigned short* __restrict__ uh,
              unsigned short* __restrict__ ul, int layer) {
    int t = blockIdx.x, d = blockIdx.y;
    const float* ysr = ys + ((size_t)d*LL + t)*DI;
    const float* zr = zx + ((size_t)d*LL + t)*DIN;
    const float* rg = rms_g + (size_t)(d*NL + layer)*DI;
    unsigned short* uhr = uh + ((size_t)d*LL + t)*DI;
    unsigned short* ulr = ul + ((size_t)d*LL + t)*DI;
    int c2 = threadIdx.x * 2;
    float2 yv = *(const float2*)(ysr + c2);    // already includes Dp*xs
    float2 zv = *(const float2*)(zr + c2);
    float u0 = yv.x * siluf(zv.x);
    float u1 = yv.y * siluf(zv.y);
    float ss = u0*u0 + u1*u1;
    float tot = blockReduceSum256(ss);
    float scale = rsqrtf(tot / DI + 1e-5f);
    float2 rgv = *(const float2*)(rg + c2);
    float o0 = u0 * scale * rgv.x;
    float o1 = u1 * scale * rgv.y;
    unsigned short h0 = bf16_rn(o0), h1 = bf16_rn(o1);
    unsigned short l0 = bf16_rn(o0 - bf16_to_f(h0)), l1 = bf16_rn(o1 - bf16_to_f(h1));
    *(unsigned*)(uhr + c2) = (unsigned)h0 | ((unsigned)h1 << 16);
    *(unsigned*)(ulr + c2) = (unsigned)l0 | ((unsigned)l1 << 16);
}

// ---------------- launch ----------------
extern "C" void kernel_launch(void* const* d_in, const int* in_sizes, int n_in,
                              void* d_out, int out_size, void* d_ws, size_t ws_size,
                              hipStream_t stream) {
    const float* vectors   = (const float*)d_in[0];
    const int*   coords    = (const int*)d_in[1];
    const float* ln_g      = (const float*)d_in[2];
    const float* ln_b      = (const float*)d_in[3];
    const float* Win       = (const float*)d_in[4];
    const float* conv_w    = (const float*)d_in[5];
    const float* conv_b    = (const float*)d_in[6];
    const float* dt_bias   = (const float*)d_in[7];
    const float* A_log     = (const float*)d_in[8];
    const float* Dp        = (const float*)d_in[9];
    const float* rms_g     = (const float*)d_in[10];
    const float* Wout      = (const float*)d_in[11];
    const float* fuse_ln_g = (const float*)d_in[12];
    const float* fuse_ln_b = (const float*)d_in[13];
    const float* fuse_W    = (const float*)d_in[14];
    const float* fuse_b    = (const float*)d_in[15];
    float* out = (float*)d_out;

    char* ws = (char*)d_ws;
    size_t off = 0;
    auto alloc = [&](size_t bytes) -> void* {
        void* p = ws + off;
        off += (bytes + 255) & ~(size_t)255;
        return p;
    };
    int* perm  = (int*)alloc((size_t)NDIR*LL*4);
    int* rank  = (int*)alloc((size_t)NDIR*LL*4);
    float* x   = (float*)alloc((size_t)NDIR*LL*DD0*4);
    unsigned short* xnh = (unsigned short*)alloc((size_t)NDIR*LL*DD0*2);
    unsigned short* xnl = (unsigned short*)alloc((size_t)NDIR*LL*DD0*2);
    float* zx  = (float*)alloc((size_t)NDIR*LL*DIN*4);
    float* Cbuf= (float*)alloc((size_t)NDIR*LL*NN*4);
    float* ysb = (float*)alloc((size_t)NDIR*LL*DI*4);
    unsigned short* uh = (unsigned short*)alloc((size_t)NDIR*LL*DI*2);
    unsigned short* ul = (unsigned short*)alloc((size_t)NDIR*LL*DI*2);
    float* cstate = (float*)alloc((size_t)NDIR*NC*HH*PP*NN*4);
    float* cumdec = (float*)alloc((size_t)NDIR*LL*HH*4);
    float* pbuf  = (float*)alloc((size_t)4*LL*DD0*4);
    unsigned short* WinTh  = (unsigned short*)alloc((size_t)NDIR*NL*DIN*DD0*2);
    unsigned short* WinTl  = (unsigned short*)alloc((size_t)NDIR*NL*DIN*DD0*2);
    unsigned short* WoutTh = (unsigned short*)alloc((size_t)NDIR*NL*DD0*DI*2);
    unsigned short* WoutTl = (unsigned short*)alloc((size_t)NDIR*NL*DD0*DI*2);
    unsigned short* fWTh   = (unsigned short*)alloc((size_t)DD0*(NDIR*DD0)*2);
    unsigned short* fWTl   = (unsigned short*)alloc((size_t)DD0*(NDIR*DD0)*2);
    // mdn hi/lo aliased onto the (dead by then) uh/ul region
    unsigned short* mdnh = uh;                                // 1024*1536 shorts = 3.1MB
    unsigned short* mdnl = ul;                                // 1024*1536 shorts
    (void)ws_size;

    sort_kernel<<<dim3(4, NDIR), 1024, 0, stream>>>(coords, perm, rank);

    // all weight transposes + hi/lo splits in ONE dispatch
    tsplit_all<<<5280, 256, 0, stream>>>(Win, Wout, fuse_W,
                                         WinTh, WinTl, WoutTh, WoutTl, fWTh, fWTl);

    for (int l = 0; l < NL; ++l) {
        if (l == 0)
            gather_ln<<<dim3(LL, NDIR), 256, 0, stream>>>(vectors, perm, x, xnh, xnl, ln_g, ln_b);
        else
            ln_split<<<dim3(LL, NDIR), 256, 0, stream>>>(x, xnh, xnl, ln_g + l*DD0, ln_b + l*DD0,
                                                         DD0, LL, NL*DD0);
        mfma_gemm<0,64><<<dim3((DIN+63)/64, LL/64, NDIR), 256, 0, stream>>>(
            xnh, xnl, WinTh + (size_t)l*DIN*DD0, WinTl + (size_t)l*DIN*DD0, zx,
            DIN, DD0, (size_t)LL*DD0, (size_t)NL*DIN*DD0, (size_t)LL*DIN, nullptr, 0);
        conv_scan1<<<NDIR*HH*NC, 256, 0, stream>>>(zx, conv_w, conv_b, dt_bias, A_log, Dp,
                                                   ysb, Cbuf, cstate, cumdec, l);
        scan_pass2<<<NDIR*HH, 256, 0, stream>>>(cstate, cumdec);
        scan_pass3<<<NDIR*HH*NC, 256, 0, stream>>>(Cbuf, cumdec, cstate, ysb);
        gate_rms<<<dim3(LL, NDIR), 256, 0, stream>>>(ysb, zx, rms_g, uh, ul, l);
        mfma_gemm<1,64><<<dim3(DD0/64, LL/64, NDIR), 256, 0, stream>>>(
            uh, ul, WoutTh + (size_t)l*DD0*DI, WoutTl + (size_t)l*DD0*DI, x,
            DD0, DI, (size_t)LL*DI, (size_t)NL*DD0*DI, (size_t)LL*DD0, nullptr, 0);
    }

    ln_concat<<<LL, 256, 0, stream>>>(x, rank, mdnh, mdnl, fuse_ln_g, fuse_ln_b);
    // fuse GEMM: split-K over 4 chunks of 384 (12 K-tiles each) -> partials -> reduce+gelu
    mfma_gemm<3,64><<<dim3(DD0/64, LL/64, 4), 256, 0, stream>>>(
        mdnh, mdnl, fWTh, fWTl, pbuf, DD0, NDIR*DD0, 0, 0, (size_t)LL*DD0, nullptr, 12);
    reduce_gelu<<<LL, 256, 0, stream>>>(pbuf, fuse_b, out);
}

// Round 14
// 271.883 us; speedup vs baseline: 1.0577x; 1.0577x over previous
//
#include <hip/hip_runtime.h>
#include <hip/hip_bf16.h>
#include <cstddef>

// Problem constants
#define LL 1024
#define DD0 256
#define NDIR 6
#define NL 2
#define HH 8
#define PP 64
#define NN 32
#define KK 4
#define DI 512           // 2*D
#define DIN 1096         // 2*DI + 2*N + H
#define CONV_DIM 576     // DI + 2*N

// chunked scan config (QC=32 is the measured optimum: 64->32 won (R4), 32->16 lost (R13))
#define QC 32            // chunk length
#define NC 32            // LL / QC
#define NCSH 5           // log2(NC)

__constant__ int c_ord[6][3] = {{0,1,2},{0,2,1},{1,0,2},{1,2,0},{2,0,1},{2,1,0}};

typedef __attribute__((ext_vector_type(8))) short bf16x8;
typedef __attribute__((ext_vector_type(4))) float f32x4;

// ---------------- helpers ----------------
__device__ inline float blockReduceSum256(float v) {
    __shared__ float sred[4];
#pragma unroll
    for (int off = 1; off < 64; off <<= 1) v += __shfl_xor(v, off);
    int lane = threadIdx.x & 63, w = threadIdx.x >> 6;
    __syncthreads();               // protect sred from a previous call
    if (lane == 0) sred[w] = v;
    __syncthreads();
    return sred[0] + sred[1] + sred[2] + sred[3];
}

__device__ inline float siluf(float x) { return x / (1.f + expf(-x)); }

// round-to-nearest-even fp32 -> bf16 bits
__device__ inline unsigned short bf16_rn(float x) {
    unsigned u = __float_as_uint(x);
    unsigned r = (u + 0x7fffu + ((u >> 16) & 1u)) >> 16;
    return (unsigned short)r;
}
__device__ inline float bf16_to_f(unsigned short h) {
    return __uint_as_float(((unsigned)h) << 16);
}

// ---------------- sort (lexsort via rank counting, 4-way split) ----------------
__global__ __launch_bounds__(1024)
void sort_kernel(const int* __restrict__ coords, int* __restrict__ perm, int* __restrict__ rank) {
    int q = blockIdx.x, d = blockIdx.y;
    int tid = threadIdx.x;
    __shared__ unsigned keys[LL];
    __shared__ unsigned short part[256][5];
    int a0 = c_ord[d][0], a1 = c_ord[d][1], a2 = c_ord[d][2];
    {
        unsigned c0 = (unsigned)coords[tid*4 + a0];
        unsigned c1 = (unsigned)coords[tid*4 + a1];
        unsigned c2 = (unsigned)coords[tid*4 + a2];
        keys[tid] = (c0 << 22) | (c1 << 16) | (c2 << 10) | (unsigned)tid;
    }
    __syncthreads();
    int il = tid >> 2, jq = tid & 3;
    int i = q*256 + il;
    unsigned ki = keys[i];
    int r = 0;
    int j0 = jq*256;
#pragma unroll 8
    for (int j = j0; j < j0 + 256; ++j) r += (keys[j] < ki) ? 1 : 0;
    part[il][jq] = (unsigned short)r;
    __syncthreads();
    if (tid < 256) {
        int i2 = q*256 + tid;
        int rr = part[tid][0] + part[tid][1] + part[tid][2] + part[tid][3];
        perm[d*LL + rr] = i2;
        rank[d*LL + i2] = rr;
    }
}

// ---------------- fused gather + layer-0 layernorm -> residual + bf16 hi/lo ----------------
__global__ __launch_bounds__(256)
void gather_ln(const float* __restrict__ vectors, const int* __restrict__ perm,
               float* __restrict__ x, unsigned short* __restrict__ Yh,
               unsigned short* __restrict__ Yl,
               const float* __restrict__ g, const float* __restrict__ b) {
    int t = blockIdx.x, d = blockIdx.y, c = threadIdx.x;
    int src = perm[d*LL + t];
    float xv = vectors[(size_t)src*DD0 + c];
    x[((size_t)d*LL + t)*DD0 + c] = xv;
    float s = blockReduceSum256(xv);
    float s2 = blockReduceSum256(xv*xv);
    float mu = s / DD0;
    float var = s2 / DD0 - mu*mu;
    float inv = rsqrtf(var + 1e-5f);
    const float* gr = g + (size_t)d*NL*DD0;
    const float* br = b + (size_t)d*NL*DD0;
    float yv = (xv - mu) * inv * gr[c] + br[c];
    unsigned short h = bf16_rn(yv);
    Yh[((size_t)d*LL + t)*DD0 + c] = h;
    Yl[((size_t)d*LL + t)*DD0 + c] = bf16_rn(yv - bf16_to_f(h));
}

// ---------------- layernorm -> bf16 hi/lo split (layer 1) ----------------
__global__ __launch_bounds__(256)
void ln_split(const float* __restrict__ X, unsigned short* __restrict__ Yh,
              unsigned short* __restrict__ Yl,
              const float* __restrict__ g, const float* __restrict__ b,
              int dd, int rowsPerDir, int gstride) {
    int t = blockIdx.x, d = blockIdx.y;
    const float* xr = X + ((size_t)d*rowsPerDir + t)*dd;
    unsigned short* yh = Yh + ((size_t)d*rowsPerDir + t)*dd;
    unsigned short* yl = Yl + ((size_t)d*rowsPerDir + t)*dd;
    const float* gr = g + (size_t)d*gstride;
    const float* br = b + (size_t)d*gstride;
    float v[6];
    float s = 0.f, s2 = 0.f;
    int cnt = 0;
    for (int c = threadIdx.x; c < dd; c += 256) {
        float xv = xr[c];
        v[cnt++] = xv;
        s += xv; s2 += xv*xv;
    }
    float tot = blockReduceSum256(s);
    float tot2 = blockReduceSum256(s2);
    float mu = tot / dd;
    float var = tot2 / dd - mu*mu;
    float inv = rsqrtf(var + 1e-5f);
    cnt = 0;
    for (int c = threadIdx.x; c < dd; c += 256) {
        float yv = (v[cnt++] - mu) * inv * gr[c] + br[c];
        unsigned short h = bf16_rn(yv);
        yh[c] = h;
        yl[c] = bf16_rn(yv - bf16_to_f(h));
    }
}

// ---------------- fused inverse-permute concat + fuse layernorm ----------------
__global__ __launch_bounds__(256)
void ln_concat(const float* __restrict__ x, const int* __restrict__ rank,
               unsigned short* __restrict__ Yh, unsigned short* __restrict__ Yl,
               const float* __restrict__ g, const float* __restrict__ b) {
    int t = blockIdx.x, tid = threadIdx.x;
    float v[NDIR];
    float s = 0.f, s2 = 0.f;
#pragma unroll
    for (int d = 0; d < NDIR; ++d) {
        int r = rank[d*LL + t];
        float xv = x[((size_t)d*LL + r)*DD0 + tid];
        v[d] = xv;
        s += xv; s2 += xv*xv;
    }
    float tot = blockReduceSum256(s);
    float tot2 = blockReduceSum256(s2);
    const int dd = NDIR*DD0;
    float mu = tot / dd;
    float var = tot2 / dd - mu*mu;
    float inv = rsqrtf(var + 1e-5f);
#pragma unroll
    for (int d = 0; d < NDIR; ++d) {
        int c = d*DD0 + tid;
        float yv = (v[d] - mu) * inv * g[c] + b[c];
        unsigned short h = bf16_rn(yv);
        Yh[(size_t)t*dd + c] = h;
        Yl[(size_t)t*dd + c] = bf16_rn(yv - bf16_to_f(h));
    }
}

// ---------------- merged transpose+split for all three weights (1 dispatch) ----------
__global__ __launch_bounds__(256)
void tsplit_all(const float* __restrict__ Wi, const float* __restrict__ Wo,
                const float* __restrict__ Wf,
                unsigned short* __restrict__ WinTh, unsigned short* __restrict__ WinTl,
                unsigned short* __restrict__ WoutTh, unsigned short* __restrict__ WoutTl,
                unsigned short* __restrict__ fWTh, unsigned short* __restrict__ fWTl) {
    int bid = blockIdx.x;
    const float* W; unsigned short *Th, *Tl; int Kd, Nd, bx, by, bz;
    if (bid < 3360) {
        int r = bid; W = Wi; Th = WinTh; Tl = WinTl; Kd = DD0; Nd = DIN;
        bx = r % 35; r /= 35; by = r & 7; bz = r >> 3;
    } else if (bid < 4896) {
        int r = bid - 3360; W = Wo; Th = WoutTh; Tl = WoutTl; Kd = DI; Nd = DD0;
        bx = r & 7; r >>= 3; by = r & 15; bz = r >> 4;
    } else {
        int r = bid - 4896; W = Wf; Th = fWTh; Tl = fWTl; Kd = NDIR*DD0; Nd = DD0;
        bx = r & 7; by = r >> 3; bz = 0;
    }
    __shared__ float tile[32][33];
    int j0 = bx * 32;   // N
    int i0 = by * 32;   // K
    int c = threadIdx.x & 31, r8 = threadIdx.x >> 5;
    const float* Wz = W + (size_t)bz * Kd * Nd;
    unsigned short* Thz = Th + (size_t)bz * Nd * Kd;
    unsigned short* Tlz = Tl + (size_t)bz * Nd * Kd;
#pragma unroll
    for (int s = 0; s < 4; ++s) {
        int i = i0 + r8 + s*8;
        tile[r8 + s*8][c] = (i < Kd && (j0 + c) < Nd) ? Wz[(size_t)i*Nd + j0 + c] : 0.f;
    }
    __syncthreads();
#pragma unroll
    for (int s = 0; s < 4; ++s) {
        int j = j0 + r8 + s*8;   // output row (n)
        int i = i0 + c;          // output col (k)
        if (j < Nd && i < Kd) {
            float xv = tile[c][r8 + s*8];
            unsigned short h = bf16_rn(xv);
            Thz[(size_t)j*Kd + i] = h;
            Tlz[(size_t)j*Kd + i] = bf16_rn(xv - bf16_to_f(h));
        }
    }
}

// ---------------- split-precision MFMA GEMM, LDS + 2-deep prefetch pipeline ----------
// (R10-proven: BOTH operands LDS-staged — per-lane-strided direct fragment
// loads fragment into 16 cache lines/wave and lose, even when L2-resident.)
template<int MODE, int BM>
__global__ __launch_bounds__(256)
void mfma_gemm(const unsigned short* __restrict__ Ahg, const unsigned short* __restrict__ Alg,
               const unsigned short* __restrict__ Bhg, const unsigned short* __restrict__ Blg,
               float* __restrict__ Cg, int N, int K,
               size_t sA, size_t sB, size_t sC, const float* __restrict__ bias,
               int ksplit) {
    constexpr int MF = BM / 32;          // m-fragments per wave
    __shared__ unsigned short AhS[2][BM][40];
    __shared__ unsigned short AlS[2][BM][40];
    __shared__ unsigned short BhS[2][64][40];
    __shared__ unsigned short BlS[2][64][40];
    const unsigned short* Azh = Ahg + (MODE == 3 ? 0 : (size_t)blockIdx.z * sA);
    const unsigned short* Azl = Alg + (MODE == 3 ? 0 : (size_t)blockIdx.z * sA);
    const unsigned short* Bzh = Bhg + (MODE == 3 ? 0 : (size_t)blockIdx.z * sB);
    const unsigned short* Bzl = Blg + (MODE == 3 ? 0 : (size_t)blockIdx.z * sB);
    float* Cz = Cg + (size_t)blockIdx.z * sC;
    int row0 = blockIdx.y * BM;
    int col0 = blockIdx.x * 64;
    int tid = threadIdx.x;
    int lane = tid & 63, wid = tid >> 6;
    int mbase = (wid >> 1) * (BM/2), nbase = (wid & 1) * 32;
    int lr = lane & 15, lk = (lane >> 4) * 8;

    int ar0 = tid >> 2;
    int ar1 = 64 + (tid >> 2);
    int ac  = (tid & 3) * 8;
    int brow = tid >> 2;
    int bc8 = (tid & 3) * 8;
    bool bvalid = (col0 + brow) < N;
    const uint4 z4 = {0u,0u,0u,0u};

    f32x4 acc[MF][2];
#pragma unroll
    for (int m = 0; m < MF; ++m)
#pragma unroll
        for (int n = 0; n < 2; ++n) acc[m][n] = (f32x4){0.f, 0.f, 0.f, 0.f};

    uint4 s0a0, s0a1, s0l0, s0l1, s0bh, s0bl;
    uint4 s1a0, s1a1, s1l0, s1l1, s1bh, s1bl;

#define LOAD_TILE(Ra0,Ra1,Rl0,Rl1,Rbh,Rbl,kt) do {                          \
        size_t ka = (size_t)(kt) * 32;                                       \
        size_t g0 = (size_t)(row0 + ar0)*K + ka + ac;                        \
        Ra0 = *(const uint4*)(Azh + g0);                                     \
        Rl0 = *(const uint4*)(Azl + g0);                                     \
        if (BM == 128) {                                                     \
            size_t g1 = (size_t)(row0 + ar1)*K + ka + ac;                    \
            Ra1 = *(const uint4*)(Azh + g1);                                 \
            Rl1 = *(const uint4*)(Azl + g1);                                 \
        }                                                                    \
        if (bvalid) {                                                        \
            size_t gb = (size_t)(col0 + brow)*K + ka + bc8;                  \
            Rbh = *(const uint4*)(Bzh + gb);                                 \
            Rbl = *(const uint4*)(Bzl + gb);                                 \
        } else { Rbh = z4; Rbl = z4; }                                       \
    } while (0)

#define WRITE_TILE(buf,Ra0,Ra1,Rl0,Rl1,Rbh,Rbl) do {                         \
        *(uint4*)&AhS[buf][ar0][ac] = Ra0;                                   \
        *(uint4*)&AlS[buf][ar0][ac] = Rl0;                                   \
        if (BM == 128) {                                                     \
            *(uint4*)&AhS[buf][ar1 & (BM-1)][ac] = Ra1;                      \
            *(uint4*)&AlS[buf][ar1 & (BM-1)][ac] = Rl1;                      \
        }                                                                    \
        *(uint4*)&BhS[buf][brow][bc8] = Rbh;                                 \
        *(uint4*)&BlS[buf][brow][bc8] = Rbl;                                 \
    } while (0)

#define COMPUTE(buf) do {                                                    \
        bf16x8 afh[MF], afl[MF], bfh[2], bfl[2];                             \
        _Pragma("unroll")                                                    \
        for (int mf = 0; mf < MF; ++mf) {                                    \
            afh[mf] = *(const bf16x8*)&AhS[buf][mbase + mf*16 + lr][lk];     \
            afl[mf] = *(const bf16x8*)&AlS[buf][mbase + mf*16 + lr][lk];     \
        }                                                                    \
        _Pragma("unroll")                                                    \
        for (int nf = 0; nf < 2; ++nf) {                                     \
            bfh[nf] = *(const bf16x8*)&BhS[buf][nbase + nf*16 + lr][lk];     \
            bfl[nf] = *(const bf16x8*)&BlS[buf][nbase + nf*16 + lr][lk];     \
        }                                                                    \
        _Pragma("unroll")                                                    \
        for (int mf = 0; mf < MF; ++mf)                                      \
            _Pragma("unroll")                                                \
            for (int nf = 0; nf < 2; ++nf) {                                 \
                acc[mf][nf] = __builtin_amdgcn_mfma_f32_16x16x32_bf16(afh[mf], bfh[nf], acc[mf][nf], 0, 0, 0); \
                acc[mf][nf] = __builtin_amdgcn_mfma_f32_16x16x32_bf16(afh[mf], bfl[nf], acc[mf][nf], 0, 0, 0); \
                acc[mf][nf] = __builtin_amdgcn_mfma_f32_16x16x32_bf16(afl[mf], bfh[nf], acc[mf][nf], 0, 0, 0); \
            }                                                                \
    } while (0)

    int nt, kt0;
    if (MODE == 3) { nt = ksplit; kt0 = (int)blockIdx.z * ksplit; }
    else           { nt = K >> 5; kt0 = 0; }

    LOAD_TILE(s0a0, s0a1, s0l0, s0l1, s0bh, s0bl, kt0 + 0);
    LOAD_TILE(s1a0, s1a1, s1l0, s1l1, s1bh, s1bl, kt0 + 1);
    WRITE_TILE(0, s0a0, s0a1, s0l0, s0l1, s0bh, s0bl);
    __syncthreads();

    for (int t = 0; t < nt; t += 2) {
        if (t + 2 < nt) LOAD_TILE(s0a0, s0a1, s0l0, s0l1, s0bh, s0bl, kt0 + t + 2);
        COMPUTE(0);
        WRITE_TILE(1, s1a0, s1a1, s1l0, s1l1, s1bh, s1bl);
        __syncthreads();
        if (t + 3 < nt) LOAD_TILE(s1a0, s1a1, s1l0, s1l1, s1bh, s1bl, kt0 + t + 3);
        COMPUTE(1);
        if (t + 2 < nt) WRITE_TILE(0, s0a0, s0a1, s0l0, s0l1, s0bh, s0bl);
        __syncthreads();
    }

#undef LOAD_TILE
#undef WRITE_TILE
#undef COMPUTE

    int crb = (lane >> 4) * 4;
    int cco = lane & 15;
#pragma unroll
    for (int mf = 0; mf < MF; ++mf) {
#pragma unroll
        for (int nf = 0; nf < 2; ++nf) {
            int col = col0 + nbase + nf*16 + cco;
            if (col < N) {
#pragma unroll
                for (int r = 0; r < 4; ++r) {
                    int row = row0 + mbase + mf*16 + crb + r;
                    size_t o = (size_t)row*N + col;
                    float vv = acc[mf][nf][r];
                    if (MODE == 0 || MODE == 3) Cz[o] = vv;
                    else if (MODE == 1) Cz[o] += vv;
                    else {
                        vv += bias[col];
                        Cz[o] = 0.5f * vv * (1.f + erff(vv * 0.70710678118654752f));
                    }
                }
            }
        }
    }
}

// ---------------- split-K reduce + bias + gelu ----------------
__global__ __launch_bounds__(256)
void reduce_gelu(const float* __restrict__ pbuf, const float* __restrict__ bias,
                 float* __restrict__ out) {
    int t = blockIdx.x, c = threadIdx.x;
    size_t o = (size_t)t*DD0 + c;
    const size_t st = (size_t)LL*DD0;
    float v = pbuf[o] + pbuf[o + st] + pbuf[o + 2*st] + pbuf[o + 3*st] + bias[c];
    out[o] = 0.5f * v * (1.f + erff(v * 0.70710678118654752f));
}

// ---------------- FUSED conv(K=4)+silu + chunk-local selective scan ----------------
__global__ __launch_bounds__(256)
void conv_scan1(const float* __restrict__ zx, const float* __restrict__ conv_w,
                const float* __restrict__ conv_b, const float* __restrict__ dt_bias,
                const float* __restrict__ A_log, const float* __restrict__ Dp,
                float* __restrict__ ys, float* __restrict__ Cbuf,
                float* __restrict__ cstate, float* __restrict__ cumdec, int layer) {
    int bid = blockIdx.x;
    int c = bid & (NC - 1);
    int hd = bid >> NCSH;
    int d = hd >> 3, h = hd & 7;
    int tid = threadIdx.x;
    int t0 = c * QC;

    __shared__ float sxc[QC][132];   // cols 0..63 = xs slice, 64..95 = B, 96..127 = C
    __shared__ float sdt[QC];
    __shared__ float sdA[QC];

    const float* Z = zx + (size_t)d*LL*DIN;

    // ---- phase A: conv for 128 cols x 32 t ----
    {
        int col = tid & 127;
        int half = tid >> 7;            // 2 halves x 16 t
        int tstart = t0 + half*16;
        int realc = (col < 64) ? (h*PP + col) : ((col < 96) ? (DI + (col-64)) : (DI + NN + (col-96)));
        int zxcol = DI + realc;
        const float* wr = conv_w + ((size_t)(d*NL + layer)*CONV_DIM + realc)*KK;
        float w0 = wr[0], w1 = wr[1], w2 = wr[2], w3 = wr[3];
        float bias = conv_b[(size_t)(d*NL + layer)*CONV_DIM + realc];
        float z0 = (tstart-3 >= 0) ? Z[(size_t)(tstart-3)*DIN + zxcol] : 0.f;
        float z1 = (tstart-2 >= 0) ? Z[(size_t)(tstart-2)*DIN + zxcol] : 0.f;
        float z2 = (tstart-1 >= 0) ? Z[(size_t)(tstart-1)*DIN + zxcol] : 0.f;
#pragma unroll
        for (int tt = 0; tt < 16; ++tt) {
            int t = tstart + tt;
            float z3 = Z[(size_t)t*DIN + zxcol];
            float acc = bias;
            acc = fmaf(z0, w0, acc);
            acc = fmaf(z1, w1, acc);
            acc = fmaf(z2, w2, acc);
            acc = fmaf(z3, w3, acc);
            sxc[half*16 + tt][col] = siluf(acc);
            z0 = z1; z1 = z2; z2 = z3;
        }
    }
    // ---- phase A2: dt / dA for this h ----
    if (tid < QC) {
        int t = t0 + tid;
        float v = Z[(size_t)t*DIN + (DIN - HH) + h] + dt_bias[(d*NL + layer)*HH + h];
        float sp = (v > 20.f) ? v : log1pf(expf(v));
        sdt[tid] = sp;
        sdA[tid] = expf(-expf(A_log[(d*NL + layer)*HH + h]) * sp);
    }
    __syncthreads();

    // ---- phase B: chunk-local scan from LDS ----
    int p = tid >> 2, g = tid & 3, n0 = g << 3;
    float dpv = Dp[(d*NL + layer)*HH + h];
    float* ysd = ys + (size_t)d*LL*DI + h*PP + p;
    float* cdd = cumdec + (size_t)d*LL*HH + h;
    float* Cbd = Cbuf + (size_t)d*LL*NN;

    float hs[8];
#pragma unroll
    for (int j = 0; j < 8; ++j) hs[j] = 0.f;
    float cum = 1.f;

    for (int tt = 0; tt < QC; ++tt) {
        float dtv = sdt[tt], dAv = sdA[tt];
        float xv = sxc[tt][p];
        float dtx = dtv * xv;
        float4 b0 = *(const float4*)&sxc[tt][64 + n0];
        float4 b1 = *(const float4*)&sxc[tt][64 + n0 + 4];
        float4 c0 = *(const float4*)&sxc[tt][96 + n0];
        float4 c1 = *(const float4*)&sxc[tt][96 + n0 + 4];
        float B[8] = {b0.x,b0.y,b0.z,b0.w,b1.x,b1.y,b1.z,b1.w};
        float Cv[8] = {c0.x,c0.y,c0.z,c0.w,c1.x,c1.y,c1.z,c1.w};
        float acc = 0.f;
#pragma unroll
        for (int j = 0; j < 8; ++j) {
            hs[j] = fmaf(dAv, hs[j], dtx * B[j]);
            acc = fmaf(hs[j], Cv[j], acc);
        }
        acc += __shfl_xor(acc, 1);
        acc += __shfl_xor(acc, 2);
        int t = t0 + tt;
        if (g == 0) ysd[(size_t)t*DI] = acc + dpv * xv;     // D-residual folded in
        else if (g == 2 && h == 0 && p < NN) Cbd[(size_t)t*NN + p] = sxc[tt][96 + p];
        cum *= dAv;
        if (tid == 0) cdd[(size_t)t*HH] = cum;
    }

    float* cs = cstate + (((size_t)(d*NC + c)*HH + h)*PP + p)*NN + n0;
    float4 s0 = {hs[0], hs[1], hs[2], hs[3]};
    float4 s1 = {hs[4], hs[5], hs[6], hs[7]};
    *(float4*)cs = s0;
    *(float4*)(cs + 4) = s1;
}

// ---------------- pass2: sequential fixup over chunk states ----------------
__global__ __launch_bounds__(256)
void scan_pass2(float* __restrict__ cstate, const float* __restrict__ cumdec) {
    int hd = blockIdx.x;
    int d = hd >> 3, h = hd & 7;
    int tid = threadIdx.x;
    int p = tid >> 2, g = tid & 3, n0 = g << 3;
    float carry[8];
#pragma unroll
    for (int j = 0; j < 8; ++j) carry[j] = 0.f;
    for (int c = 0; c < NC; ++c) {
        float* cs = cstate + (((size_t)(d*NC + c)*HH + h)*PP + p)*NN + n0;
        float4 s0 = *(const float4*)cs;
        float4 s1 = *(const float4*)(cs + 4);
        float4 w0 = {carry[0], carry[1], carry[2], carry[3]};
        float4 w1 = {carry[4], carry[5], carry[6], carry[7]};
        *(float4*)cs = w0;
        *(float4*)(cs + 4) = w1;
        float dec = cumdec[((size_t)d*LL + (c*QC + QC - 1))*HH + h];
        float s[8] = {s0.x,s0.y,s0.z,s0.w,s1.x,s1.y,s1.z,s1.w};
#pragma unroll
        for (int j = 0; j < 8; ++j) carry[j] = fmaf(dec, carry[j], s[j]);
    }
}

// ---------------- pass3: y[t] += cumdec[t] * (C[t] . h_init) ----------------
__global__ __launch_bounds__(256)
void scan_pass3(const float* __restrict__ Cbuf, const float* __restrict__ cumdec,
                const float* __restrict__ cstate, float* __restrict__ ys) {
    int bid = blockIdx.x;
    int c = bid & (NC - 1);
    if (c == 0) return;
    int hd = bid >> NCSH;
    int d = hd >> 3, h = hd & 7;
    int tid = threadIdx.x;
    int p = tid >> 2, g = tid & 3, n0 = g << 3;
    int t0 = c * QC;

    __shared__ float scd[QC];
    if (tid < QC) scd[tid] = cumdec[((size_t)d*LL + t0 + tid)*HH + h];

    const float* cs = cstate + (((size_t)(d*NC + c)*HH + h)*PP + p)*NN + n0;
    float4 h0 = *(const float4*)cs;
    float4 h1 = *(const float4*)(cs + 4);
    float hi[8] = {h0.x,h0.y,h0.z,h0.w,h1.x,h1.y,h1.z,h1.w};
    __syncthreads();

    const float* Cbd = Cbuf + (size_t)d*LL*NN;
    float* ysd = ys + (size_t)d*LL*DI + h*PP + p;

    for (int tt = 0; tt < QC; ++tt) {
        int t = t0 + tt;
        const float* row = Cbd + (size_t)t*NN;
        float4 c0 = *(const float4*)(row + n0);
        float4 c1 = *(const float4*)(row + n0 + 4);
        float Cv[8] = {c0.x,c0.y,c0.z,c0.w,c1.x,c1.y,c1.z,c1.w};
        float acc = 0.f;
#pragma unroll
        for (int j = 0; j < 8; ++j) acc = fmaf(hi[j], Cv[j], acc);
        acc += __shfl_xor(acc, 1);
        acc += __shfl_xor(acc, 2);
        if (g == 0) ysd[(size_t)t*DI] += scd[tt] * acc;
    }
}

// ---------------- gating + RMSNorm -> bf16 hi/lo split (float2-vectorized) --------
__global__ __launch_bounds__(256)
void gate_rms(const float* __restrict__ ys, const float* __restrict__ zx,
              const float* __restrict__ rms_g, unsigned short* __restrict__ uh,
              unsigned short* __restrict__ ul, int layer) {
    int t = blockIdx.x, d = blockIdx.y;
    const float* ysr = ys + ((size_t)d*LL + t)*DI;
    const float* zr = zx + ((size_t)d*LL + t)*DIN;
    const float* rg = rms_g + (size_t)(d*NL + layer)*DI;
    unsigned short* uhr = uh + ((size_t)d*LL + t)*DI;
    unsigned short* ulr = ul + ((size_t)d*LL + t)*DI;
    int c2 = threadIdx.x * 2;
    float2 yv = *(const float2*)(ysr + c2);    // already includes Dp*xs
    float2 zv = *(const float2*)(zr + c2);
    float u0 = yv.x * siluf(zv.x);
    float u1 = yv.y * siluf(zv.y);
    float ss = u0*u0 + u1*u1;
    float tot = blockReduceSum256(ss);
    float scale = rsqrtf(tot / DI + 1e-5f);
    float2 rgv = *(const float2*)(rg + c2);
    float o0 = u0 * scale * rgv.x;
    float o1 = u1 * scale * rgv.y;
    unsigned short h0 = bf16_rn(o0), h1 = bf16_rn(o1);
    unsigned short l0 = bf16_rn(o0 - bf16_to_f(h0)), l1 = bf16_rn(o1 - bf16_to_f(h1));
    *(unsigned*)(uhr + c2) = (unsigned)h0 | ((unsigned)h1 << 16);
    *(unsigned*)(ulr + c2) = (unsigned)l0 | ((unsigned)l1 << 16);
}

// ---------------- launch ----------------
extern "C" void kernel_launch(void* const* d_in, const int* in_sizes, int n_in,
                              void* d_out, int out_size, void* d_ws, size_t ws_size,
                              hipStream_t stream) {
    const float* vectors   = (const float*)d_in[0];
    const int*   coords    = (const int*)d_in[1];
    const float* ln_g      = (const float*)d_in[2];
    const float* ln_b      = (const float*)d_in[3];
    const float* Win       = (const float*)d_in[4];
    const float* conv_w    = (const float*)d_in[5];
    const float* conv_b    = (const float*)d_in[6];
    const float* dt_bias   = (const float*)d_in[7];
    const float* A_log     = (const float*)d_in[8];
    const float* Dp        = (const float*)d_in[9];
    const float* rms_g     = (const float*)d_in[10];
    const float* Wout      = (const float*)d_in[11];
    const float* fuse_ln_g = (const float*)d_in[12];
    const float* fuse_ln_b = (const float*)d_in[13];
    const float* fuse_W    = (const float*)d_in[14];
    const float* fuse_b    = (const float*)d_in[15];
    float* out = (float*)d_out;

    char* ws = (char*)d_ws;
    size_t off = 0;
    auto alloc = [&](size_t bytes) -> void* {
        void* p = ws + off;
        off += (bytes + 255) & ~(size_t)255;
        return p;
    };
    int* perm  = (int*)alloc((size_t)NDIR*LL*4);
    int* rank  = (int*)alloc((size_t)NDIR*LL*4);
    float* x   = (float*)alloc((size_t)NDIR*LL*DD0*4);
    unsigned short* xnh = (unsigned short*)alloc((size_t)NDIR*LL*DD0*2);
    unsigned short* xnl = (unsigned short*)alloc((size_t)NDIR*LL*DD0*2);
    float* zx  = (float*)alloc((size_t)NDIR*LL*DIN*4);
    float* Cbuf= (float*)alloc((size_t)NDIR*LL*NN*4);
    float* ysb = (float*)alloc((size_t)NDIR*LL*DI*4);
    unsigned short* uh = (unsigned short*)alloc((size_t)NDIR*LL*DI*2);
    unsigned short* ul = (unsigned short*)alloc((size_t)NDIR*LL*DI*2);
    float* cstate = (float*)alloc((size_t)NDIR*NC*HH*PP*NN*4);
    float* cumdec = (float*)alloc((size_t)NDIR*LL*HH*4);
    float* pbuf  = (float*)alloc((size_t)4*LL*DD0*4);
    unsigned short* WinTh  = (unsigned short*)alloc((size_t)NDIR*NL*DIN*DD0*2);
    unsigned short* WinTl  = (unsigned short*)alloc((size_t)NDIR*NL*DIN*DD0*2);
    unsigned short* WoutTh = (unsigned short*)alloc((size_t)NDIR*NL*DD0*DI*2);
    unsigned short* WoutTl = (unsigned short*)alloc((size_t)NDIR*NL*DD0*DI*2);
    unsigned short* fWTh   = (unsigned short*)alloc((size_t)DD0*(NDIR*DD0)*2);
    unsigned short* fWTl   = (unsigned short*)alloc((size_t)DD0*(NDIR*DD0)*2);
    // mdn hi/lo aliased onto the (dead by then) uh/ul region
    unsigned short* mdnh = uh;                                // 1024*1536 shorts = 3.1MB
    unsigned short* mdnl = ul;                                // 1024*1536 shorts
    (void)ws_size;

    sort_kernel<<<dim3(4, NDIR), 1024, 0, stream>>>(coords, perm, rank);

    // all weight transposes + hi/lo splits in ONE dispatch
    tsplit_all<<<5280, 256, 0, stream>>>(Win, Wout, fuse_W,
                                         WinTh, WinTl, WoutTh, WoutTl, fWTh, fWTl);

    for (int l = 0; l < NL; ++l) {
        if (l == 0)
            gather_ln<<<dim3(LL, NDIR), 256, 0, stream>>>(vectors, perm, x, xnh, xnl, ln_g, ln_b);
        else
            ln_split<<<dim3(LL, NDIR), 256, 0, stream>>>(x, xnh, xnl, ln_g + l*DD0, ln_b + l*DD0,
                                                         DD0, LL, NL*DD0);
        mfma_gemm<0,64><<<dim3((DIN+63)/64, LL/64, NDIR), 256, 0, stream>>>(
            xnh, xnl, WinTh + (size_t)l*DIN*DD0, WinTl + (size_t)l*DIN*DD0, zx,
            DIN, DD0, (size_t)LL*DD0, (size_t)NL*DIN*DD0, (size_t)LL*DIN, nullptr, 0);
        conv_scan1<<<NDIR*HH*NC, 256, 0, stream>>>(zx, conv_w, conv_b, dt_bias, A_log, Dp,
                                                   ysb, Cbuf, cstate, cumdec, l);
        scan_pass2<<<NDIR*HH, 256, 0, stream>>>(cstate, cumdec);
        scan_pass3<<<NDIR*HH*NC, 256, 0, stream>>>(Cbuf, cumdec, cstate, ysb);
        gate_rms<<<dim3(LL, NDIR), 256, 0, stream>>>(ysb, zx, rms_g, uh, ul, l);
        mfma_gemm<1,64><<<dim3(DD0/64, LL/64, NDIR), 256, 0, stream>>>(
            uh, ul, WoutTh + (size_t)l*DD0*DI, WoutTl + (size_t)l*DD0*DI, x,
            DD0, DI, (size_t)LL*DI, (size_t)NL*DD0*DI, (size_t)LL*DD0, nullptr, 0);
    }

    ln_concat<<<LL, 256, 0, stream>>>(x, rank, mdnh, mdnl, fuse_ln_g, fuse_ln_b);
    // fuse GEMM: split-K over 4 chunks of 384 (12 K-tiles each) -> partials -> reduce+gelu
    mfma_gemm<3,64><<<dim3(DD0/64, LL/64, 4), 256, 0, stream>>>(
        mdnh, mdnl, fWTh, fWTl, pbuf, DD0, NDIR*DD0, 0, 0, (size_t)LL*DD0, nullptr, 12);
    reduce_gelu<<<LL, 256, 0, stream>>>(pbuf, fuse_b, out);
}